// Round 1
// baseline (4337.996 us; speedup 1.0000x reference)
//
#include <hip/hip_runtime.h>

// SimpleGCN: 2-layer GCN, N=100000 nodes, E=1.6M edges, 128 -> 128(relu) -> 64.
// out = Ahat @ relu(Ahat @ (x@W1) + b1) @ W2 + b2, Ahat = D^-1/2 (A+I) D^-1/2
// (deg = in-degree by dst incl self-loop; norm[e] = dis[src]*dis[dst])

constexpr int BLK = 256;

__global__ void init_deg_kernel(float* __restrict__ deg, int n) {
    int i = blockIdx.x * BLK + threadIdx.x;
    if (i < n) deg[i] = 1.0f;
}

__global__ void count_deg_kernel(const int* __restrict__ dst, float* __restrict__ deg, int e) {
    int i = blockIdx.x * BLK + threadIdx.x;
    if (i < e) atomicAdd(&deg[dst[i]], 1.0f);
}

__global__ void to_dis_kernel(float* __restrict__ deg, int n) {
    int i = blockIdx.x * BLK + threadIdx.x;
    if (i < n) deg[i] = rsqrtf(deg[i]);
}

__device__ __forceinline__ void fma4(float4& acc, float a, const float4& b) {
    acc.x = fmaf(a, b.x, acc.x);
    acc.y = fmaf(a, b.y, acc.y);
    acc.z = fmaf(a, b.z, acc.z);
    acc.w = fmaf(a, b.w, acc.w);
}

// C[nrows][COLS] = A[nrows][128] @ B[128][COLS]   (optionally relu(A))
// Block computes RPB rows x COLS cols; thread: 4 rows x 4 cols micro-tile.
template <int COLS, int RPB, bool RELU>
__global__ __launch_bounds__(256)
void gemm_k128(const float* __restrict__ A, const float* __restrict__ B,
               float* __restrict__ C, int nrows) {
    constexpr int CG = COLS / 4;     // float4 col-groups per row
    constexpr int RG = 256 / CG;     // row-groups of threads
    constexpr int RPT = RPB / RG;    // rows per thread
    static_assert(RPT == 4, "tile mismatch");

    __shared__ float sB[128 * COLS];
    __shared__ float sA[RPB][128];

    const int t = threadIdx.x;
    const int rowbase = blockIdx.x * RPB;

    // Stage full B (128 x COLS) into LDS.
    const float4* B4 = (const float4*)B;
    float4* sB4 = (float4*)sB;
#pragma unroll
    for (int i = t; i < 128 * COLS / 4; i += 256) sB4[i] = B4[i];

    // Stage A tile (RPB x 128) into LDS, optional relu on load.
    const float4* A4 = (const float4*)A;
    for (int i = t; i < RPB * 32; i += 256) {
        int r = i >> 5, c4 = i & 31;
        int gr = rowbase + r;
        float4 v = make_float4(0.f, 0.f, 0.f, 0.f);
        if (gr < nrows) v = A4[gr * 32 + c4];
        if (RELU) {
            v.x = fmaxf(v.x, 0.f); v.y = fmaxf(v.y, 0.f);
            v.z = fmaxf(v.z, 0.f); v.w = fmaxf(v.w, 0.f);
        }
        *(float4*)&sA[r][c4 * 4] = v;
    }
    __syncthreads();

    const int tc = t % CG;
    const int tr = (t / CG) * RPT;

    float4 acc0 = make_float4(0.f, 0.f, 0.f, 0.f);
    float4 acc1 = acc0, acc2 = acc0, acc3 = acc0;

#pragma unroll 4
    for (int kq = 0; kq < 32; ++kq) {
        const int k = kq * 4;
        float4 a0 = *(const float4*)&sA[tr + 0][k];
        float4 a1 = *(const float4*)&sA[tr + 1][k];
        float4 a2 = *(const float4*)&sA[tr + 2][k];
        float4 a3 = *(const float4*)&sA[tr + 3][k];
        float4 b0 = sB4[(k + 0) * CG + tc];
        float4 b1 = sB4[(k + 1) * CG + tc];
        float4 b2 = sB4[(k + 2) * CG + tc];
        float4 b3 = sB4[(k + 3) * CG + tc];
        fma4(acc0, a0.x, b0); fma4(acc0, a0.y, b1); fma4(acc0, a0.z, b2); fma4(acc0, a0.w, b3);
        fma4(acc1, a1.x, b0); fma4(acc1, a1.y, b1); fma4(acc1, a1.z, b2); fma4(acc1, a1.w, b3);
        fma4(acc2, a2.x, b0); fma4(acc2, a2.y, b1); fma4(acc2, a2.z, b2); fma4(acc2, a2.w, b3);
        fma4(acc3, a3.x, b0); fma4(acc3, a3.y, b1); fma4(acc3, a3.z, b2); fma4(acc3, a3.w, b3);
    }

    float4* C4 = (float4*)C;
    int gr = rowbase + tr;
    if (gr + 0 < nrows) C4[(gr + 0) * CG + tc] = acc0;
    if (gr + 1 < nrows) C4[(gr + 1) * CG + tc] = acc1;
    if (gr + 2 < nrows) C4[(gr + 2) * CG + tc] = acc2;
    if (gr + 3 < nrows) C4[(gr + 3) * CG + tc] = acc3;
}

// out[node][:] = bias + dis[node]^2 * h[node][:]   (self-loop message + bias; full overwrite)
template <int C>
__global__ void self_bias_kernel(const float* __restrict__ h, const float* __restrict__ dis,
                                 const float* __restrict__ bias, float* __restrict__ out, int n) {
    constexpr int L = C / 4;
    int gid = blockIdx.x * BLK + threadIdx.x;
    int node = gid / L;
    int lane = gid % L;
    if (node >= n) return;
    float d = dis[node];
    float w = d * d;
    float4 v = ((const float4*)h)[gid];      // gid == node*L + lane
    float4 b = ((const float4*)bias)[lane];
    float4 o;
    o.x = fmaf(w, v.x, b.x);
    o.y = fmaf(w, v.y, b.y);
    o.z = fmaf(w, v.z, b.z);
    o.w = fmaf(w, v.w, b.w);
    ((float4*)out)[gid] = o;
}

// agg[dst][:] += dis[src]*dis[dst] * h[src][:]  — (C/4) lanes cooperate per edge.
template <int C>
__global__ void scatter_kernel(const int* __restrict__ src, const int* __restrict__ dst,
                               const float* __restrict__ dis, const float* __restrict__ h,
                               float* __restrict__ agg, int e) {
    constexpr int L = C / 4;
    int gid = blockIdx.x * BLK + threadIdx.x;
    int ed = gid / L;
    int lane = gid % L;
    if (ed >= e) return;
    int s = src[ed];
    int d = dst[ed];
    float w = dis[s] * dis[d];
    float4 v = ((const float4*)h)[s * L + lane];
    float* out = agg + (size_t)d * C + lane * 4;
    atomicAdd(out + 0, w * v.x);
    atomicAdd(out + 1, w * v.y);
    atomicAdd(out + 2, w * v.z);
    atomicAdd(out + 3, w * v.w);
}

extern "C" void kernel_launch(void* const* d_in, const int* in_sizes, int n_in,
                              void* d_out, int out_size, void* d_ws, size_t ws_size,
                              hipStream_t stream) {
    const float* x  = (const float*)d_in[0];
    const int*   ei = (const int*)d_in[1];
    const float* W1 = (const float*)d_in[2];
    const float* b1 = (const float*)d_in[3];
    const float* W2 = (const float*)d_in[4];
    const float* b2 = (const float*)d_in[5];
    float* out = (float*)d_out;

    const int n = in_sizes[0] / 128;   // 100000
    const int e = in_sizes[1] / 2;     // 1600000
    const int* src = ei;
    const int* dst = ei + e;

    char* ws = (char*)d_ws;
    float* dis  = (float*)ws;                       // n floats (400 KB)
    float* h    = (float*)(ws + (512u << 10));      // n*128 f32 = 51.2 MB
    float* agg1 = (float*)(ws + 52428800u);         // n*128 f32 = 51.2 MB
    float* h2   = h;                                // reuse (h dead after scatter1)

    const int nb_n = (n + BLK - 1) / BLK;
    const int nb_e = (e + BLK - 1) / BLK;

    // --- normalization ---
    init_deg_kernel<<<nb_n, BLK, 0, stream>>>(dis, n);
    count_deg_kernel<<<nb_e, BLK, 0, stream>>>(dst, dis, e);
    to_dis_kernel<<<nb_n, BLK, 0, stream>>>(dis, n);

    // --- layer 1: h = x @ W1 ; agg1 = b1 + dis^2*h + scatter ---
    gemm_k128<128, 32, false><<<(n + 31) / 32, BLK, 0, stream>>>(x, W1, h, n);
    self_bias_kernel<128><<<(n * 32 + BLK - 1) / BLK, BLK, 0, stream>>>(h, dis, b1, agg1, n);
    scatter_kernel<128><<<(int)(((long)e * 32 + BLK - 1) / BLK), BLK, 0, stream>>>(src, dst, dis, h, agg1, e);

    // --- layer 2: h2 = relu(agg1) @ W2 ; out = b2 + dis^2*h2 + scatter ---
    gemm_k128<64, 64, true><<<(n + 63) / 64, BLK, 0, stream>>>(agg1, W2, h2, n);
    self_bias_kernel<64><<<(n * 16 + BLK - 1) / BLK, BLK, 0, stream>>>(h2, dis, b2, out, n);
    scatter_kernel<64><<<(int)(((long)e * 16 + BLK - 1) / BLK), BLK, 0, stream>>>(src, dst, dis, h2, out, e);
}

// Round 2
// 554.847 us; speedup vs baseline: 7.8184x; 7.8184x over previous
//
#include <hip/hip_runtime.h>

// SimpleGCN: 2-layer GCN, N=100000 nodes, E=1.6M edges, 128 -> 128(relu) -> 64.
// out = Ahat @ relu(Ahat @ (x@W1) + b1) @ W2 + b2, Ahat = D^-1/2 (A+I) D^-1/2
//
// R2: atomic f32 scatter (3.28 GB HBM write-through, 2.67 ms) replaced by
// device-built CSR (dst-sorted) + per-node register-accumulated gather.

constexpr int BLK = 256;

// ---------------- normalization + CSR build ----------------

__global__ void init_int_kernel(int* __restrict__ p, int n) {
    int i = blockIdx.x * BLK + threadIdx.x;
    if (i < n) p[i] = 0;
}

__global__ void count_deg_kernel(const int* __restrict__ dst, int* __restrict__ deg, int e) {
    int i = blockIdx.x * BLK + threadIdx.x;
    if (i < e) atomicAdd(&deg[dst[i]], 1);
}

__global__ void dis_kernel(const int* __restrict__ deg, float* __restrict__ dis, int n) {
    int i = blockIdx.x * BLK + threadIdx.x;
    if (i < n) dis[i] = rsqrtf((float)(deg[i] + 1));  // +1 self-loop
}

// Exclusive scan of deg[n] -> rowptr[n] (within-block), block totals -> bsum.
// Block b handles int4 chunk [b*256, b*256+256) of n/4 int4s.
__global__ __launch_bounds__(256)
void scan_blocks_kernel(const int* __restrict__ deg, int* __restrict__ rowptr,
                        int* __restrict__ bsum, int n4) {
    __shared__ int ssum[256];
    const int t = threadIdx.x;
    const int i4 = blockIdx.x * 256 + t;
    int4 d = make_int4(0, 0, 0, 0);
    if (i4 < n4) d = ((const int4*)deg)[i4];
    const int s = d.x + d.y + d.z + d.w;
    ssum[t] = s;
    __syncthreads();
    for (int off = 1; off < 256; off <<= 1) {
        int v = (t >= off) ? ssum[t - off] : 0;
        __syncthreads();
        ssum[t] += v;
        __syncthreads();
    }
    const int excl = ssum[t] - s;
    if (i4 < n4) {
        int4 o;
        o.x = excl;
        o.y = o.x + d.x;
        o.z = o.y + d.y;
        o.w = o.z + d.z;
        ((int4*)rowptr)[i4] = o;
    }
    if (t == 255) bsum[blockIdx.x] = ssum[255];
}

__global__ void scan_bsum_kernel(int* __restrict__ bsum, int* __restrict__ rowptr,
                                 int n, int nb) {
    if (threadIdx.x == 0) {
        int acc = 0;
        for (int b = 0; b < nb; ++b) { int v = bsum[b]; bsum[b] = acc; acc += v; }
        rowptr[n] = acc;  // == e
    }
}

__global__ void scan_add_kernel(int* __restrict__ rowptr, const int* __restrict__ bsum, int n4) {
    int i4 = blockIdx.x * 256 + threadIdx.x;
    if (i4 >= n4) return;
    int off = bsum[blockIdx.x];
    int4 v = ((int4*)rowptr)[i4];
    v.x += off; v.y += off; v.z += off; v.w += off;
    ((int4*)rowptr)[i4] = v;
}

__global__ void fill_csr_kernel(const int* __restrict__ src, const int* __restrict__ dst,
                                const int* __restrict__ rowptr, int* __restrict__ cursor,
                                int* __restrict__ esrc, int e) {
    int i = blockIdx.x * BLK + threadIdx.x;
    if (i >= e) return;
    int d = dst[i];
    int pos = atomicAdd(&cursor[d], 1);
    esrc[rowptr[d] + pos] = src[i];
}

// ---------------- dense GEMM (K=128, f32 vector ALU) ----------------

__device__ __forceinline__ void fma4(float4& acc, float a, const float4& b) {
    acc.x = fmaf(a, b.x, acc.x);
    acc.y = fmaf(a, b.y, acc.y);
    acc.z = fmaf(a, b.z, acc.z);
    acc.w = fmaf(a, b.w, acc.w);
}

template <int COLS, int RPB, bool RELU>
__global__ __launch_bounds__(256)
void gemm_k128(const float* __restrict__ A, const float* __restrict__ B,
               float* __restrict__ C, int nrows) {
    constexpr int CG = COLS / 4;
    constexpr int RG = 256 / CG;
    constexpr int RPT = RPB / RG;
    static_assert(RPT == 4, "tile mismatch");

    __shared__ float sB[128 * COLS];
    __shared__ float sA[RPB][128];

    const int t = threadIdx.x;
    const int rowbase = blockIdx.x * RPB;

    const float4* B4 = (const float4*)B;
    float4* sB4 = (float4*)sB;
#pragma unroll
    for (int i = t; i < 128 * COLS / 4; i += 256) sB4[i] = B4[i];

    const float4* A4 = (const float4*)A;
    for (int i = t; i < RPB * 32; i += 256) {
        int r = i >> 5, c4 = i & 31;
        int gr = rowbase + r;
        float4 v = make_float4(0.f, 0.f, 0.f, 0.f);
        if (gr < nrows) v = A4[gr * 32 + c4];
        if (RELU) {
            v.x = fmaxf(v.x, 0.f); v.y = fmaxf(v.y, 0.f);
            v.z = fmaxf(v.z, 0.f); v.w = fmaxf(v.w, 0.f);
        }
        *(float4*)&sA[r][c4 * 4] = v;
    }
    __syncthreads();

    const int tc = t % CG;
    const int tr = (t / CG) * RPT;

    float4 acc0 = make_float4(0.f, 0.f, 0.f, 0.f);
    float4 acc1 = acc0, acc2 = acc0, acc3 = acc0;

#pragma unroll 4
    for (int kq = 0; kq < 32; ++kq) {
        const int k = kq * 4;
        float4 a0 = *(const float4*)&sA[tr + 0][k];
        float4 a1 = *(const float4*)&sA[tr + 1][k];
        float4 a2 = *(const float4*)&sA[tr + 2][k];
        float4 a3 = *(const float4*)&sA[tr + 3][k];
        float4 b0 = sB4[(k + 0) * CG + tc];
        float4 b1 = sB4[(k + 1) * CG + tc];
        float4 b2 = sB4[(k + 2) * CG + tc];
        float4 b3 = sB4[(k + 3) * CG + tc];
        fma4(acc0, a0.x, b0); fma4(acc0, a0.y, b1); fma4(acc0, a0.z, b2); fma4(acc0, a0.w, b3);
        fma4(acc1, a1.x, b0); fma4(acc1, a1.y, b1); fma4(acc1, a1.z, b2); fma4(acc1, a1.w, b3);
        fma4(acc2, a2.x, b0); fma4(acc2, a2.y, b1); fma4(acc2, a2.z, b2); fma4(acc2, a2.w, b3);
        fma4(acc3, a3.x, b0); fma4(acc3, a3.y, b1); fma4(acc3, a3.z, b2); fma4(acc3, a3.w, b3);
    }

    float4* C4 = (float4*)C;
    int gr = rowbase + tr;
    if (gr + 0 < nrows) C4[(gr + 0) * CG + tc] = acc0;
    if (gr + 1 < nrows) C4[(gr + 1) * CG + tc] = acc1;
    if (gr + 2 < nrows) C4[(gr + 2) * CG + tc] = acc2;
    if (gr + 3 < nrows) C4[(gr + 3) * CG + tc] = acc3;
}

// ---------------- CSR gather-aggregate ----------------
// out[i][:] = bias + dis[i] * ( dis[i]*h[i][:] + sum_{s in N(i)} dis[s]*h[s][:] )
// L = C/4 lanes per node; each edge row read = L*16B contiguous.
template <int C>
__global__ __launch_bounds__(256)
void gather_csr_kernel(const int* __restrict__ rowptr, const int* __restrict__ esrc,
                       const float* __restrict__ dis, const float* __restrict__ h,
                       const float* __restrict__ bias, float* __restrict__ out, int n) {
    constexpr int L = C / 4;
    const int gid = blockIdx.x * BLK + threadIdx.x;
    const int node = gid / L;
    const int lane = gid % L;
    if (node >= n) return;

    const float4* h4 = (const float4*)h;
    const float di = dis[node];
    const int start = rowptr[node];
    const int end = rowptr[node + 1];

    // self-loop term carries weight di*di: fold one di now, one at the end.
    float4 v = h4[node * L + lane];
    float4 acc;
    acc.x = di * v.x; acc.y = di * v.y; acc.z = di * v.z; acc.w = di * v.w;

    int k = start;
    for (; k + 1 < end; k += 2) {  // 2-way unroll for memory-level parallelism
        int s0 = esrc[k], s1 = esrc[k + 1];
        float w0 = dis[s0], w1 = dis[s1];
        float4 v0 = h4[s0 * L + lane];
        float4 v1 = h4[s1 * L + lane];
        fma4(acc, w0, v0);
        fma4(acc, w1, v1);
    }
    if (k < end) {
        int s0 = esrc[k];
        fma4(acc, dis[s0], h4[s0 * L + lane]);
    }

    float4 b = ((const float4*)bias)[lane];
    float4 o;
    o.x = fmaf(di, acc.x, b.x);
    o.y = fmaf(di, acc.y, b.y);
    o.z = fmaf(di, acc.z, b.z);
    o.w = fmaf(di, acc.w, b.w);
    ((float4*)out)[gid] = o;
}

// ---------------- launch ----------------

extern "C" void kernel_launch(void* const* d_in, const int* in_sizes, int n_in,
                              void* d_out, int out_size, void* d_ws, size_t ws_size,
                              hipStream_t stream) {
    const float* x  = (const float*)d_in[0];
    const int*   ei = (const int*)d_in[1];
    const float* W1 = (const float*)d_in[2];
    const float* b1 = (const float*)d_in[3];
    const float* W2 = (const float*)d_in[4];
    const float* b2 = (const float*)d_in[5];
    float* out = (float*)d_out;

    const int n = in_sizes[0] / 128;  // 100000
    const int e = in_sizes[1] / 2;    // 1600000
    const int* src = ei;
    const int* dst = ei + e;

    char* ws = (char*)d_ws;
    float* dis    = (float*)(ws + 0);            // 400 KB slot
    int*   deg    = (int*)  (ws + 0x80000);      // 512K: n ints
    int*   rowptr = (int*)  (ws + 0x100000);     // 1M: n+1 ints
    int*   cursor = (int*)  (ws + 0x180000);     // 1.5M: n ints
    int*   bsum   = (int*)  (ws + 0x200000);     // 2M: ~98 ints
    int*   esrc   = (int*)  (ws + 0x210000);     // 2M+64K: e ints (6.4 MB)
    float* h      = (float*)(ws + 0x900000);     // 9M: n*128 f32 (51.2 MB)
    float* agg1   = (float*)(ws + 0x3A00000);    // 58M: n*128 f32 (51.2 MB)
    float* h2     = h;                           // h dead after gather1

    const int nb_n = (n + BLK - 1) / BLK;
    const int nb_e = (e + BLK - 1) / BLK;
    const int n4 = n / 4;                        // 25000 (n % 4 == 0)
    const int nb_scan = (n4 + 255) / 256;        // 98

    // normalization + CSR
    init_int_kernel<<<nb_n, BLK, 0, stream>>>(deg, n);
    count_deg_kernel<<<nb_e, BLK, 0, stream>>>(dst, deg, e);
    dis_kernel<<<nb_n, BLK, 0, stream>>>(deg, dis, n);
    scan_blocks_kernel<<<nb_scan, 256, 0, stream>>>(deg, rowptr, bsum, n4);
    scan_bsum_kernel<<<1, 64, 0, stream>>>(bsum, rowptr, n, nb_scan);
    scan_add_kernel<<<nb_scan, 256, 0, stream>>>(rowptr, bsum, n4);
    init_int_kernel<<<nb_n, BLK, 0, stream>>>(cursor, n);
    fill_csr_kernel<<<nb_e, BLK, 0, stream>>>(src, dst, rowptr, cursor, esrc, e);

    // layer 1: h = x @ W1 ; agg1 = gather(h) + b1
    gemm_k128<128, 32, false><<<(n + 31) / 32, BLK, 0, stream>>>(x, W1, h, n);
    gather_csr_kernel<128><<<(n * 32 + BLK - 1) / BLK, BLK, 0, stream>>>(
        rowptr, esrc, dis, h, b1, agg1, n);

    // layer 2: h2 = relu(agg1) @ W2 ; out = gather(h2) + b2
    gemm_k128<64, 64, true><<<(n + 63) / 64, BLK, 0, stream>>>(agg1, W2, h2, n);
    gather_csr_kernel<64><<<(n * 16 + BLK - 1) / BLK, BLK, 0, stream>>>(
        rowptr, esrc, dis, h2, b2, out, n);
}